// Round 17
// baseline (101.448 us; speedup 1.0000x reference)
//
#include <hip/hip_runtime.h>

// GNN layer (fp32 in/out):
//   out_i = (e_i@W1^T + b1 + b2) + dinv_i * sum_{j in N(i)} z_j
//   z_j   = dinv_j * (e_j@W1^T + e_j^2@W2^T)
// (refactor of: (e + L e)@W1^T + b1 + (L e^2)@W2^T + b2, L = D^-1/2 A D^-1/2)
// Pipeline (5 kernels): count -> scan+wfrag -> scatter -> sort+MFMA-xform
// (fused) -> fp8 gather-sum.
// HW rules learned on this problem:
//  (r4) sub-dword global stores -> ECC RMW amplification. Pack to >=4B.
//  (r5) scattered 4B stores write ~64B/line (cross-XCD migration).
//  (r6) scattered global atomics: same writeback physics.
//  (r7) scattered RETURNING atomics: ~32B/op write-through to HBM.
//  (r8) dense [n,64]@[64,64] on VALU is LDS-issue-bound -> MFMA (G10).
//  (r9/r10/r14) gather FETCH scales with row width; 2.46 TB/s random-line
//       service ceiling. (r15) fp8 e4m3 z-rows (64B = 1 line) -> -7.8us.
//  (r11) nt hints: REGRESSION. (r12) bipartite split: NEUTRAL.
//  (r13) cooperative build fusion: REGRESSION (1 block/CU kills parallelism).
//  (r16) k4_fused at 564 blocks = 2.2/CU -> latency-bound at 14% occupancy.
// r17: 128-node buckets (nbuck=1127 -> 4.4 blocks/CU, ~2x occupancy for the
//      fused sort+xform); rec pack (v<<7)|(u&127); RECCAP 4096.

#define NB 256          // blocks for count/scatter passes (must equal blockDim)
#define BSH 7           // log2(bucket size)
#define BSZ 128         // nodes per bucket
#define BMASK 127
#define MAXBUCK 1216    // bucket arrays sized for nbuck = ceil(n/128) = 1127
#define RECCAP 4096     // k4 LDS record cache (max 128-node bucket ~2.6K records)
#define ZSCALE 64.0f
#define ZINV (1.0f / 64.0f)

typedef short bf16x8 __attribute__((ext_vector_type(8)));
typedef float f32x4 __attribute__((ext_vector_type(4)));

__device__ __forceinline__ float bflo(unsigned int u) {
    union { unsigned int i; float f; } c; c.i = u << 16; return c.f;
}
__device__ __forceinline__ float bfhi(unsigned int u) {
    union { unsigned int i; float f; } c; c.i = u & 0xffff0000u; return c.f;
}
__device__ __forceinline__ unsigned int f2bf(float f) {
    union { float f; unsigned int i; } c; c.f = f;
    unsigned int r = c.i + 0x7FFFu + ((c.i >> 16) & 1u);  // RTN-even
    return r >> 16;
}
__device__ __forceinline__ unsigned int pk2(float a, float b) {
    return f2bf(a) | (f2bf(b) << 16);
}

// ---------------- CSR build: two-level LDS counting sort ----------------

__global__ __launch_bounds__(256) void k1_count(const int* __restrict__ row,
                                                const int* __restrict__ col,
                                                int* __restrict__ H,
                                                int* __restrict__ galloc,
                                                int Eh, int nbuck) {
    __shared__ int hist[MAXBUCK];
    int tid = threadIdx.x, b = blockIdx.x;
    if (b == 0 && tid == 0) *galloc = 0;   // consumed by k2 (strictly after k1)
    for (int i = tid; i < nbuck; i += 256) hist[i] = 0;
    __syncthreads();
    int chunk = (((Eh + NB - 1) / NB) + 3) & ~3;
    int e0 = b * chunk;
    int len = Eh - e0;
    if (len > chunk) len = chunk;
    if (len < 0) len = 0;
    int len4 = len & ~3;
    for (int o = tid * 4; o < len4; o += 1024) {
        int4 u = *(const int4*)&row[e0 + o];
        int4 v = *(const int4*)&col[e0 + o];
        atomicAdd(&hist[u.x >> BSH], 1); atomicAdd(&hist[v.x >> BSH], 1);
        atomicAdd(&hist[u.y >> BSH], 1); atomicAdd(&hist[v.y >> BSH], 1);
        atomicAdd(&hist[u.z >> BSH], 1); atomicAdd(&hist[v.z >> BSH], 1);
        atomicAdd(&hist[u.w >> BSH], 1); atomicAdd(&hist[v.w >> BSH], 1);
    }
    if (tid < len - len4) {
        int e = e0 + len4 + tid;
        atomicAdd(&hist[row[e] >> BSH], 1);
        atomicAdd(&hist[col[e] >> BSH], 1);
    }
    __syncthreads();
    for (int i = tid; i < nbuck; i += 256) H[b * nbuck + i] = hist[i];
}

// Per-bucket scan over blocks + atomic region allocation; spare blocks 0..3
// also build the fragment-ordered weight buffer wfrag[(m,t,kf,lane)] (int4 =
// 8 bf16 = W[m][16t+L][kf*32+hi*8 .. +7], L=lane&15, hi=lane>>4).
__global__ __launch_bounds__(256) void k2_colscan(const int* __restrict__ H,
                                                  int* __restrict__ Off,
                                                  int* __restrict__ btot,
                                                  int* __restrict__ bbase,
                                                  int* __restrict__ galloc,
                                                  const float4* __restrict__ W1_4,
                                                  const float4* __restrict__ W2_4,
                                                  int4* __restrict__ wfrag, int nbuck) {
    __shared__ int lds[256];
    int t = threadIdx.x, beta = blockIdx.x;
    int v = H[t * nbuck + beta];
    lds[t] = v;
    __syncthreads();
    for (int off = 1; off < 256; off <<= 1) {
        int x = (t >= off) ? lds[t - off] : 0;
        __syncthreads();
        lds[t] += x;
        __syncthreads();
    }
    Off[beta * NB + t] = lds[t] - v;
    if (t == 255) {
        int tot = lds[255];
        btot[beta] = tot;
        bbase[beta] = atomicAdd(galloc, tot);
    }
    if (beta < 4) {
        int idx = beta * 256 + t;            // 0..1023
        int m = idx >> 9, tt = (idx >> 7) & 3, kf = (idx >> 6) & 1;
        int lane = idx & 63, L = lane & 15, hi = lane >> 4;
        int rowd = 16 * tt + L;
        const float4* Wp = (m ? W2_4 : W1_4) + (size_t)rowd * 16 + kf * 8 + hi * 2;
        float4 w0 = Wp[0], w1 = Wp[1];
        wfrag[idx] = make_int4(pk2(w0.x, w0.y), pk2(w0.z, w0.w),
                               pk2(w1.x, w1.y), pk2(w1.z, w1.w));
    }
}

// rec packing: (v<<BSH) | (u&BMASK); bucket of u implicit from region.
__global__ __launch_bounds__(256) void k3_scatter(const int* __restrict__ row,
                                                  const int* __restrict__ col,
                                                  const int* __restrict__ Off,
                                                  const int* __restrict__ bbase,
                                                  unsigned int* __restrict__ rec,
                                                  int Eh, int nbuck) {
    __shared__ int cur[MAXBUCK];
    int tid = threadIdx.x, b = blockIdx.x;
    for (int i = tid; i < nbuck; i += 256) cur[i] = bbase[i] + Off[i * NB + b];
    __syncthreads();
    int chunk = (((Eh + NB - 1) / NB) + 3) & ~3;   // MUST match k1
    int e0 = b * chunk;
    int len = Eh - e0;
    if (len > chunk) len = chunk;
    if (len < 0) len = 0;
    int len4 = len & ~3;
    for (int o = tid * 4; o < len4; o += 1024) {
        int4 u = *(const int4*)&row[e0 + o];
        int4 v = *(const int4*)&col[e0 + o];
        int p;
        p = atomicAdd(&cur[u.x >> BSH], 1); rec[p] = ((unsigned int)v.x << BSH) | (u.x & BMASK);
        p = atomicAdd(&cur[v.x >> BSH], 1); rec[p] = ((unsigned int)u.x << BSH) | (v.x & BMASK);
        p = atomicAdd(&cur[u.y >> BSH], 1); rec[p] = ((unsigned int)v.y << BSH) | (u.y & BMASK);
        p = atomicAdd(&cur[v.y >> BSH], 1); rec[p] = ((unsigned int)u.y << BSH) | (v.y & BMASK);
        p = atomicAdd(&cur[u.z >> BSH], 1); rec[p] = ((unsigned int)v.z << BSH) | (u.z & BMASK);
        p = atomicAdd(&cur[v.z >> BSH], 1); rec[p] = ((unsigned int)u.z << BSH) | (v.z & BMASK);
        p = atomicAdd(&cur[u.w >> BSH], 1); rec[p] = ((unsigned int)v.w << BSH) | (u.w & BMASK);
        p = atomicAdd(&cur[v.w >> BSH], 1); rec[p] = ((unsigned int)u.w << BSH) | (v.w & BMASK);
    }
    if (tid < len - len4) {
        int e = e0 + len4 + tid;
        int u = row[e], v = col[e];
        int p = atomicAdd(&cur[u >> BSH], 1);
        rec[p] = ((unsigned int)v << BSH) | (u & BMASK);
        int q = atomicAdd(&cur[v >> BSH], 1);
        rec[q] = ((unsigned int)u << BSH) | (v & BMASK);
    }
}

// ---------------- fused: per-bucket counting sort + MFMA transform ----------
// Sort: exact CSR (sse={start,end}, dinv, scol) for the bucket's 128 nodes.
// Xform: 2 rounds x (4 waves x 16-node tiles), mfma_f32_16x16x32_bf16;
// B-fragments from wfrag (loaded once per block), degrees from LDS hist.
// Epilogue: y1p dword L=(L,16+L), 16+L=(32+L,48+L);
//           zp8 dword L = fp8 dims {L,16+L,32+L,48+L} x ZSCALE.
__global__ __launch_bounds__(256) void k4_fused(
    const unsigned int* __restrict__ rec, const int* __restrict__ bbase,
    const int* __restrict__ btot, int2* __restrict__ sse,
    float* __restrict__ dinv, int* __restrict__ scol,
    const float4* __restrict__ embed4, const int4* __restrict__ wfrag,
    const float* __restrict__ b1, const float* __restrict__ b2,
    unsigned int* __restrict__ y1p, unsigned int* __restrict__ zp8, int n) {
    __shared__ int hist[BSZ], lcur[BSZ], lds[BSZ];
    __shared__ unsigned int cache[RECCAP];
    int t = threadIdx.x, beta = blockIdx.x;
    int base = bbase[beta];
    int cnt = btot[beta];
    bool cached = cnt <= RECCAP;
    if (t < BSZ) hist[t] = 0;
    __syncthreads();
    for (int r = t; r < cnt; r += 256) {
        unsigned int rr = rec[base + r];
        if (cached) cache[r] = rr;
        atomicAdd(&hist[rr & BMASK], 1);
    }
    __syncthreads();
    int h = (t < BSZ) ? hist[t] : 0;
    if (t < BSZ) lds[t] = h;
    __syncthreads();
    for (int off = 1; off < BSZ; off <<= 1) {
        int x = (t >= off && t < BSZ) ? lds[t - off] : 0;
        __syncthreads();
        if (t < BSZ) lds[t] += x;
        __syncthreads();
    }
    int excl = (t < BSZ) ? lds[t] - h : 0;
    int node0 = (beta << BSH) + t;
    if (t < BSZ && node0 < n) {
        sse[node0] = make_int2(base + excl, base + excl + h);
        dinv[node0] = h > 0 ? rsqrtf((float)h) : 0.0f;
    }
    if (t < BSZ) lcur[t] = base + excl;
    __syncthreads();
    for (int r = t; r < cnt; r += 256) {
        unsigned int rr = cached ? cache[r] : rec[base + r];
        int p = atomicAdd(&lcur[rr & BMASK], 1);
        scol[p] = (int)(rr >> BSH);
    }
    // hist[] (degrees) is stable from here; lcur/lds no longer needed.

    int wave = t >> 6, lane = t & 63;
    int L = lane & 15, hi = lane >> 4;

    bf16x8 bfr[2][4][2];
#pragma unroll
    for (int m = 0; m < 2; m++)
#pragma unroll
        for (int tt = 0; tt < 4; tt++)
#pragma unroll
            for (int kf = 0; kf < 2; kf++) {
                int4 raw = wfrag[((((m * 4 + tt) * 2) + kf) << 6) + lane];
                bfr[m][tt][kf] = *(bf16x8*)&raw;
            }

    float bs0 = b1[L] + b2[L];
    float bs1 = b1[16 + L] + b2[16 + L];
    float bs2 = b1[32 + L] + b2[32 + L];
    float bs3 = b1[48 + L] + b2[48 + L];

    for (int rnd = 0; rnd < 2; rnd++) {
        int loc16 = rnd * 64 + wave * 16;          // bucket-local tile base
        int tb16 = (beta << BSH) + loc16;
        int nodeA = tb16 + L;
        int nc = nodeA < n ? nodeA : n - 1;
        const float4* rowp = embed4 + (size_t)nc * 16;
        float4 a0 = rowp[hi * 2];
        float4 a1 = rowp[hi * 2 + 1];
        float4 a2 = rowp[8 + hi * 2];
        float4 a3 = rowp[8 + hi * 2 + 1];

        int4 e0 = make_int4(pk2(a0.x, a0.y), pk2(a0.z, a0.w), pk2(a1.x, a1.y), pk2(a1.z, a1.w));
        int4 e1 = make_int4(pk2(a2.x, a2.y), pk2(a2.z, a2.w), pk2(a3.x, a3.y), pk2(a3.z, a3.w));
        int4 q0 = make_int4(pk2(a0.x * a0.x, a0.y * a0.y), pk2(a0.z * a0.z, a0.w * a0.w),
                            pk2(a1.x * a1.x, a1.y * a1.y), pk2(a1.z * a1.z, a1.w * a1.w));
        int4 q1 = make_int4(pk2(a2.x * a2.x, a2.y * a2.y), pk2(a2.z * a2.z, a2.w * a2.w),
                            pk2(a3.x * a3.x, a3.y * a3.y), pk2(a3.z * a3.z, a3.w * a3.w));
        bf16x8 aE[2] = {*(bf16x8*)&e0, *(bf16x8*)&e1};
        bf16x8 aQ[2] = {*(bf16x8*)&q0, *(bf16x8*)&q1};

        f32x4 accY[4], accS[4];
#pragma unroll
        for (int tt = 0; tt < 4; tt++) { accY[tt] = (f32x4)0.f; accS[tt] = (f32x4)0.f; }
#pragma unroll
        for (int kf = 0; kf < 2; kf++)
#pragma unroll
            for (int tt = 0; tt < 4; tt++) {
                accY[tt] = __builtin_amdgcn_mfma_f32_16x16x32_bf16(aE[kf], bfr[0][tt][kf], accY[tt], 0, 0, 0);
                accS[tt] = __builtin_amdgcn_mfma_f32_16x16x32_bf16(aQ[kf], bfr[1][tt][kf], accS[tt], 0, 0, 0);
            }

#pragma unroll
        for (int r = 0; r < 4; r++) {
            int node = tb16 + 4 * hi + r;
            if (node >= n) continue;
            int hd = hist[loc16 + 4 * hi + r];
            float di = hd > 0 ? rsqrtf((float)hd) : 0.0f;
            float y0 = accY[0][r], y1 = accY[1][r], y2 = accY[2][r], y3 = accY[3][r];
            float s0 = accS[0][r], s1 = accS[1][r], s2 = accS[2][r], s3 = accS[3][r];
            size_t b32 = (size_t)node * 32;
            y1p[b32 + L]      = pk2(y0 + bs0, y1 + bs1);   // dims (L, 16+L)
            y1p[b32 + 16 + L] = pk2(y2 + bs2, y3 + bs3);   // dims (32+L, 48+L)
            float z0 = di * (y0 + s0) * ZSCALE;
            float z1 = di * (y1 + s1) * ZSCALE;
            float z2 = di * (y2 + s2) * ZSCALE;
            float z3 = di * (y3 + s3) * ZSCALE;
            int w = __builtin_amdgcn_cvt_pk_fp8_f32(z0, z1, 0, false);
            w = __builtin_amdgcn_cvt_pk_fp8_f32(z2, z3, w, true);
            zp8[(size_t)node * 16 + L] = (unsigned int)w;
        }
    }
}

// ---------------- fp8 gather-sum ----------------
// 16-lane group per node, 4 nodes/wave. z-row = 64B (one line); lane l's
// dword holds fp8 dims {l, 16+l, 32+l, 48+l} (scaled). y1 bf16, out fp32.
__global__ __launch_bounds__(256, 8) void k_main(
    const unsigned int* __restrict__ zp8, const unsigned int* __restrict__ y1p,
    const int2* __restrict__ sse, const int* __restrict__ scol,
    const float* __restrict__ dinv, float* __restrict__ outf, int n) {
    int tid = threadIdx.x;
    int wave = tid >> 6, lane = tid & 63, g = lane >> 4, l = lane & 15;
    int i = blockIdx.x * 16 + wave * 4 + g;
    bool valid = i < n;
    int ii = valid ? i : 0;
    int2 se = sse[ii];
    int s0 = se.x;
    int s1 = valid ? se.y : se.x;

    float4 acc = make_float4(0.f, 0.f, 0.f, 0.f);
    for (int e = s0; e < s1; e += 16) {
        int cnt = s1 - e;
        cnt = cnt > 16 ? 16 : cnt;
        int jv = scol[e + (l < cnt ? l : 0)];
#pragma unroll 8
        for (int k = 0; k < 16; k++) {
            int j = __shfl(jv, (g << 4) + k, 64);
            float m = (k < cnt) ? 1.0f : 0.0f;
            unsigned int w = zp8[(size_t)j * 16 + l];
            acc.x = fmaf(__builtin_amdgcn_cvt_f32_fp8(w, 0), m, acc.x);  // dim l
            acc.y = fmaf(__builtin_amdgcn_cvt_f32_fp8(w, 1), m, acc.y);  // dim 16+l
            acc.z = fmaf(__builtin_amdgcn_cvt_f32_fp8(w, 2), m, acc.z);  // dim 32+l
            acc.w = fmaf(__builtin_amdgcn_cvt_f32_fp8(w, 3), m, acc.w);  // dim 48+l
        }
    }
    if (valid) {
        float ds = dinv[i] * ZINV;
        unsigned int ya = y1p[(size_t)i * 32 + l];        // dims (l, 16+l)
        unsigned int yb = y1p[(size_t)i * 32 + 16 + l];   // dims (32+l, 48+l)
        size_t base = (size_t)i * 64;
        outf[base + l]      = fmaf(ds, acc.x, bflo(ya));
        outf[base + 16 + l] = fmaf(ds, acc.y, bfhi(ya));
        outf[base + 32 + l] = fmaf(ds, acc.z, bflo(yb));
        outf[base + 48 + l] = fmaf(ds, acc.w, bfhi(yb));
    }
}

extern "C" void kernel_launch(void* const* d_in, const int* in_sizes, int n_in,
                              void* d_out, int out_size, void* d_ws, size_t ws_size,
                              hipStream_t stream) {
    const float* embed = (const float*)d_in[0];
    const int* row = (const int*)d_in[1];
    const int* col = (const int*)d_in[2];
    const float* W1 = (const float*)d_in[3];
    const float* b1 = (const float*)d_in[4];
    const float* W2 = (const float*)d_in[5];
    const float* b2 = (const float*)d_in[6];
    float* out = (float*)d_out;

    int n = in_sizes[0] / 64;   // 144242
    int E = in_sizes[1];        // 2,000,000
    int Eh = E / 2;             // symmetric pairs: row=[u;it], col=[it;u]
    int nbuck = (n + BSZ - 1) >> BSH;  // 1127
    size_t n64 = (size_t)n * 64;
    if (nbuck > MAXBUCK) return;  // fixed-size LDS guard
    if (n >= (1 << 18)) return;   // rec packing guard (v<<BSH must fit 32b)

    char* ws = (char*)d_ws;
    size_t off = 0;
    unsigned int* zp8 = (unsigned int*)(ws + off); off += n64;            // 9.2 MB (fp8)
    unsigned int* y1p = (unsigned int*)(ws + off); off += n64 * 2;        // 18.5 MB
    unsigned int* rec = (unsigned int*)(ws + off); off += (size_t)E * 4;  // 8 MB
    int* scol = (int*)(ws + off);                  off += (size_t)E * 4;  // 8 MB
    int* H = (int*)(ws + off);                     off += (size_t)NB * nbuck * 4;
    int* Off = (int*)(ws + off);                   off += (size_t)nbuck * NB * 4;
    int* btot = (int*)(ws + off);                  off += (size_t)nbuck * 4;
    int* bbase = (int*)(ws + off);                 off += (size_t)nbuck * 4;
    int2* sse = (int2*)(ws + off);                 off += (size_t)n * 8;
    float* dinv = (float*)(ws + off);              off += (size_t)n * 4;
    int4* wfrag = (int4*)(ws + off);               off += 1024 * 16;      // 16 KB
    int* galloc = (int*)(ws + off);                off += 64;

    if (off > ws_size) return;  // ws too small -> out stays zero (0.707 absmax signal)

    k1_count<<<NB, 256, 0, stream>>>(row, col, H, galloc, Eh, nbuck);
    k2_colscan<<<nbuck, 256, 0, stream>>>(H, Off, btot, bbase, galloc,
                                          (const float4*)W1, (const float4*)W2,
                                          wfrag, nbuck);
    k3_scatter<<<NB, 256, 0, stream>>>(row, col, Off, bbase, rec, Eh, nbuck);
    k4_fused<<<nbuck, 256, 0, stream>>>(rec, bbase, btot, sse, dinv, scol,
                                        (const float4*)embed, wfrag, b1, b2,
                                        y1p, zp8, n);
    k_main<<<(n + 15) / 16, 256, 0, stream>>>(zp8, y1p, sse, scol, dinv, out, n);
}

// Round 18
// 88.866 us; speedup vs baseline: 1.1416x; 1.1416x over previous
//
#include <hip/hip_runtime.h>

// GNN layer (fp32 in/out):
//   out_i = (e_i@W1^T + b1 + b2) + dinv_i * sum_{j in N(i)} z_j
//   z_j   = dinv_j * (e_j@W1^T + e_j^2@W2^T)
// (refactor of: (e + L e)@W1^T + b1 + (L e^2)@W2^T + b2, L = D^-1/2 A D^-1/2)
// Pipeline (5 kernels): count -> scan+wfrag -> scatter -> sort+MFMA-xform
// (fused) -> fp8 gather-sum.
// HW rules learned on this problem:
//  (r4) sub-dword global stores -> ECC RMW amplification. Pack to >=4B.
//  (r5) scattered 4B stores write ~64B/line (cross-XCD migration).
//  (r6) scattered global atomics: same writeback physics.
//  (r7) scattered RETURNING atomics: ~32B/op write-through to HBM.
//  (r8) dense [n,64]@[64,64] on VALU is LDS-issue-bound -> MFMA (G10).
//  (r9/r10/r14) gather FETCH scales with row width; 2.46 TB/s random-line
//       service ceiling. (r15) fp8 e4m3 z-rows (64B = 1 line) -> -7.8us.
//  (r11) nt hints: REGRESSION. (r12) bipartite split: NEUTRAL.
//  (r13) cooperative build fusion: REGRESSION (1 block/CU kills parallelism).
//  (r16) fuse sort+xform: WIN (-6.8us). (r17) 128-node buckets: REGRESSION
//       (k4 per-block critical path unchanged -> not parallelism-bound;
//        smaller buckets cost k1/k3 ~13us). Reverted to 256-node buckets.
// r18: 4-deep software pipeline on k4's two record loops (dependent
//      global-load -> LDS-atomic chains were serializing at ~1 load/latency).

#define NB 256          // blocks for count/scatter passes (must equal blockDim)
#define MAXBUCK 608     // bucket arrays sized for nbuck = ceil(n/256) = 564
#define RECCAP 8192     // k4 LDS record cache (max bucket ~5.3K records)
#define ZSCALE 64.0f
#define ZINV (1.0f / 64.0f)

typedef short bf16x8 __attribute__((ext_vector_type(8)));
typedef float f32x4 __attribute__((ext_vector_type(4)));

__device__ __forceinline__ float bflo(unsigned int u) {
    union { unsigned int i; float f; } c; c.i = u << 16; return c.f;
}
__device__ __forceinline__ float bfhi(unsigned int u) {
    union { unsigned int i; float f; } c; c.i = u & 0xffff0000u; return c.f;
}
__device__ __forceinline__ unsigned int f2bf(float f) {
    union { float f; unsigned int i; } c; c.f = f;
    unsigned int r = c.i + 0x7FFFu + ((c.i >> 16) & 1u);  // RTN-even
    return r >> 16;
}
__device__ __forceinline__ unsigned int pk2(float a, float b) {
    return f2bf(a) | (f2bf(b) << 16);
}

// ---------------- CSR build: two-level LDS counting sort ----------------

__global__ __launch_bounds__(256) void k1_count(const int* __restrict__ row,
                                                const int* __restrict__ col,
                                                int* __restrict__ H,
                                                int* __restrict__ galloc,
                                                int Eh, int nbuck) {
    __shared__ int hist[MAXBUCK];
    int tid = threadIdx.x, b = blockIdx.x;
    if (b == 0 && tid == 0) *galloc = 0;   // consumed by k2 (strictly after k1)
    for (int i = tid; i < nbuck; i += 256) hist[i] = 0;
    __syncthreads();
    int chunk = (((Eh + NB - 1) / NB) + 3) & ~3;
    int e0 = b * chunk;
    int len = Eh - e0;
    if (len > chunk) len = chunk;
    if (len < 0) len = 0;
    int len4 = len & ~3;
    for (int o = tid * 4; o < len4; o += 1024) {
        int4 u = *(const int4*)&row[e0 + o];
        int4 v = *(const int4*)&col[e0 + o];
        atomicAdd(&hist[u.x >> 8], 1); atomicAdd(&hist[v.x >> 8], 1);
        atomicAdd(&hist[u.y >> 8], 1); atomicAdd(&hist[v.y >> 8], 1);
        atomicAdd(&hist[u.z >> 8], 1); atomicAdd(&hist[v.z >> 8], 1);
        atomicAdd(&hist[u.w >> 8], 1); atomicAdd(&hist[v.w >> 8], 1);
    }
    if (tid < len - len4) {
        int e = e0 + len4 + tid;
        atomicAdd(&hist[row[e] >> 8], 1);
        atomicAdd(&hist[col[e] >> 8], 1);
    }
    __syncthreads();
    for (int i = tid; i < nbuck; i += 256) H[b * nbuck + i] = hist[i];
}

// Per-bucket scan over blocks + atomic region allocation; spare blocks 0..3
// also build the fragment-ordered weight buffer wfrag[(m,t,kf,lane)] (int4 =
// 8 bf16 = W[m][16t+L][kf*32+hi*8 .. +7], L=lane&15, hi=lane>>4).
__global__ __launch_bounds__(256) void k2_colscan(const int* __restrict__ H,
                                                  int* __restrict__ Off,
                                                  int* __restrict__ btot,
                                                  int* __restrict__ bbase,
                                                  int* __restrict__ galloc,
                                                  const float4* __restrict__ W1_4,
                                                  const float4* __restrict__ W2_4,
                                                  int4* __restrict__ wfrag, int nbuck) {
    __shared__ int lds[256];
    int t = threadIdx.x, beta = blockIdx.x;
    int v = H[t * nbuck + beta];
    lds[t] = v;
    __syncthreads();
    for (int off = 1; off < 256; off <<= 1) {
        int x = (t >= off) ? lds[t - off] : 0;
        __syncthreads();
        lds[t] += x;
        __syncthreads();
    }
    Off[beta * NB + t] = lds[t] - v;
    if (t == 255) {
        int tot = lds[255];
        btot[beta] = tot;
        bbase[beta] = atomicAdd(galloc, tot);
    }
    if (beta < 4) {
        int idx = beta * 256 + t;            // 0..1023
        int m = idx >> 9, tt = (idx >> 7) & 3, kf = (idx >> 6) & 1;
        int lane = idx & 63, L = lane & 15, hi = lane >> 4;
        int rowd = 16 * tt + L;
        const float4* Wp = (m ? W2_4 : W1_4) + (size_t)rowd * 16 + kf * 8 + hi * 2;
        float4 w0 = Wp[0], w1 = Wp[1];
        wfrag[idx] = make_int4(pk2(w0.x, w0.y), pk2(w0.z, w0.w),
                               pk2(w1.x, w1.y), pk2(w1.z, w1.w));
    }
}

// rec packing: (v<<8) | (u&255); bucket of u implicit from region.
__global__ __launch_bounds__(256) void k3_scatter(const int* __restrict__ row,
                                                  const int* __restrict__ col,
                                                  const int* __restrict__ Off,
                                                  const int* __restrict__ bbase,
                                                  unsigned int* __restrict__ rec,
                                                  int Eh, int nbuck) {
    __shared__ int cur[MAXBUCK];
    int tid = threadIdx.x, b = blockIdx.x;
    for (int i = tid; i < nbuck; i += 256) cur[i] = bbase[i] + Off[i * NB + b];
    __syncthreads();
    int chunk = (((Eh + NB - 1) / NB) + 3) & ~3;   // MUST match k1
    int e0 = b * chunk;
    int len = Eh - e0;
    if (len > chunk) len = chunk;
    if (len < 0) len = 0;
    int len4 = len & ~3;
    for (int o = tid * 4; o < len4; o += 1024) {
        int4 u = *(const int4*)&row[e0 + o];
        int4 v = *(const int4*)&col[e0 + o];
        int p;
        p = atomicAdd(&cur[u.x >> 8], 1); rec[p] = ((unsigned int)v.x << 8) | (u.x & 255);
        p = atomicAdd(&cur[v.x >> 8], 1); rec[p] = ((unsigned int)u.x << 8) | (v.x & 255);
        p = atomicAdd(&cur[u.y >> 8], 1); rec[p] = ((unsigned int)v.y << 8) | (u.y & 255);
        p = atomicAdd(&cur[v.y >> 8], 1); rec[p] = ((unsigned int)u.y << 8) | (v.y & 255);
        p = atomicAdd(&cur[u.z >> 8], 1); rec[p] = ((unsigned int)v.z << 8) | (u.z & 255);
        p = atomicAdd(&cur[v.z >> 8], 1); rec[p] = ((unsigned int)u.z << 8) | (v.z & 255);
        p = atomicAdd(&cur[u.w >> 8], 1); rec[p] = ((unsigned int)v.w << 8) | (u.w & 255);
        p = atomicAdd(&cur[v.w >> 8], 1); rec[p] = ((unsigned int)u.w << 8) | (v.w & 255);
    }
    if (tid < len - len4) {
        int e = e0 + len4 + tid;
        int u = row[e], v = col[e];
        int p = atomicAdd(&cur[u >> 8], 1);
        rec[p] = ((unsigned int)v << 8) | (u & 255);
        int q = atomicAdd(&cur[v >> 8], 1);
        rec[q] = ((unsigned int)u << 8) | (v & 255);
    }
}

// ---------------- fused: per-bucket counting sort + MFMA transform ----------
// Sort: exact CSR (sse={start,end}, dinv, scol) for the bucket's 256 nodes.
// Record loops are 4-deep software-pipelined (r18): 4 independent loads in
// flight before any consume, breaking the load->atomic dependency chain.
// Xform: 4 rounds x (4 waves x 16-node tiles), mfma_f32_16x16x32_bf16.
__global__ __launch_bounds__(256) void k4_fused(
    const unsigned int* __restrict__ rec, const int* __restrict__ bbase,
    const int* __restrict__ btot, int2* __restrict__ sse,
    float* __restrict__ dinv, int* __restrict__ scol,
    const float4* __restrict__ embed4, const int4* __restrict__ wfrag,
    const float* __restrict__ b1, const float* __restrict__ b2,
    unsigned int* __restrict__ y1p, unsigned int* __restrict__ zp8, int n) {
    __shared__ int hist[256], lcur[256], lds[256];
    __shared__ unsigned int cache[RECCAP];
    int t = threadIdx.x, beta = blockIdx.x;
    int base = bbase[beta];
    int cnt = btot[beta];
    bool cached = cnt <= RECCAP;
    hist[t] = 0;
    __syncthreads();
    // histogram pass: 4 loads in flight per iteration
    for (int r = t; r < cnt; r += 1024) {
        int r1 = r + 256, r2 = r + 512, r3 = r + 768;
        unsigned int a0 = rec[base + r];
        unsigned int a1 = (r1 < cnt) ? rec[base + r1] : 0u;
        unsigned int a2 = (r2 < cnt) ? rec[base + r2] : 0u;
        unsigned int a3 = (r3 < cnt) ? rec[base + r3] : 0u;
        if (cached) {
            cache[r] = a0;
            if (r1 < cnt) cache[r1] = a1;
            if (r2 < cnt) cache[r2] = a2;
            if (r3 < cnt) cache[r3] = a3;
        }
        atomicAdd(&hist[a0 & 255], 1);
        if (r1 < cnt) atomicAdd(&hist[a1 & 255], 1);
        if (r2 < cnt) atomicAdd(&hist[a2 & 255], 1);
        if (r3 < cnt) atomicAdd(&hist[a3 & 255], 1);
    }
    __syncthreads();
    int h = hist[t];
    lds[t] = h;
    __syncthreads();
    for (int off = 1; off < 256; off <<= 1) {
        int x = (t >= off) ? lds[t - off] : 0;
        __syncthreads();
        lds[t] += x;
        __syncthreads();
    }
    int excl = lds[t] - h;
    int node0 = (beta << 8) + t;
    if (node0 < n) {
        sse[node0] = make_int2(base + excl, base + excl + h);
        dinv[node0] = h > 0 ? rsqrtf((float)h) : 0.0f;
    }
    lcur[t] = base + excl;
    __syncthreads();
    // scatter pass: 4-wide batches (cache-hot when cached)
    for (int r = t; r < cnt; r += 1024) {
        int r1 = r + 256, r2 = r + 512, r3 = r + 768;
        unsigned int a0 = cached ? cache[r] : rec[base + r];
        unsigned int a1 = (r1 < cnt) ? (cached ? cache[r1] : rec[base + r1]) : 0u;
        unsigned int a2 = (r2 < cnt) ? (cached ? cache[r2] : rec[base + r2]) : 0u;
        unsigned int a3 = (r3 < cnt) ? (cached ? cache[r3] : rec[base + r3]) : 0u;
        int p0 = atomicAdd(&lcur[a0 & 255], 1);
        int p1 = (r1 < cnt) ? atomicAdd(&lcur[a1 & 255], 1) : 0;
        int p2 = (r2 < cnt) ? atomicAdd(&lcur[a2 & 255], 1) : 0;
        int p3 = (r3 < cnt) ? atomicAdd(&lcur[a3 & 255], 1) : 0;
        scol[p0] = (int)(a0 >> 8);
        if (r1 < cnt) scol[p1] = (int)(a1 >> 8);
        if (r2 < cnt) scol[p2] = (int)(a2 >> 8);
        if (r3 < cnt) scol[p3] = (int)(a3 >> 8);
    }
    // hist[] (degrees) is stable from here; lcur/lds no longer needed.

    int wave = t >> 6, lane = t & 63;
    int L = lane & 15, hi = lane >> 4;

    bf16x8 bfr[2][4][2];
#pragma unroll
    for (int m = 0; m < 2; m++)
#pragma unroll
        for (int tt = 0; tt < 4; tt++)
#pragma unroll
            for (int kf = 0; kf < 2; kf++) {
                int4 raw = wfrag[((((m * 4 + tt) * 2) + kf) << 6) + lane];
                bfr[m][tt][kf] = *(bf16x8*)&raw;
            }

    float bs0 = b1[L] + b2[L];
    float bs1 = b1[16 + L] + b2[16 + L];
    float bs2 = b1[32 + L] + b2[32 + L];
    float bs3 = b1[48 + L] + b2[48 + L];

    for (int rnd = 0; rnd < 4; rnd++) {
        int loc16 = rnd * 64 + wave * 16;          // bucket-local tile base
        int tb16 = (beta << 8) + loc16;
        int nodeA = tb16 + L;
        int nc = nodeA < n ? nodeA : n - 1;
        const float4* rowp = embed4 + (size_t)nc * 16;
        float4 a0 = rowp[hi * 2];
        float4 a1 = rowp[hi * 2 + 1];
        float4 a2 = rowp[8 + hi * 2];
        float4 a3 = rowp[8 + hi * 2 + 1];

        int4 e0 = make_int4(pk2(a0.x, a0.y), pk2(a0.z, a0.w), pk2(a1.x, a1.y), pk2(a1.z, a1.w));
        int4 e1 = make_int4(pk2(a2.x, a2.y), pk2(a2.z, a2.w), pk2(a3.x, a3.y), pk2(a3.z, a3.w));
        int4 q0 = make_int4(pk2(a0.x * a0.x, a0.y * a0.y), pk2(a0.z * a0.z, a0.w * a0.w),
                            pk2(a1.x * a1.x, a1.y * a1.y), pk2(a1.z * a1.z, a1.w * a1.w));
        int4 q1 = make_int4(pk2(a2.x * a2.x, a2.y * a2.y), pk2(a2.z * a2.z, a2.w * a2.w),
                            pk2(a3.x * a3.x, a3.y * a3.y), pk2(a3.z * a3.z, a3.w * a3.w));
        bf16x8 aE[2] = {*(bf16x8*)&e0, *(bf16x8*)&e1};
        bf16x8 aQ[2] = {*(bf16x8*)&q0, *(bf16x8*)&q1};

        f32x4 accY[4], accS[4];
#pragma unroll
        for (int tt = 0; tt < 4; tt++) { accY[tt] = (f32x4)0.f; accS[tt] = (f32x4)0.f; }
#pragma unroll
        for (int kf = 0; kf < 2; kf++)
#pragma unroll
            for (int tt = 0; tt < 4; tt++) {
                accY[tt] = __builtin_amdgcn_mfma_f32_16x16x32_bf16(aE[kf], bfr[0][tt][kf], accY[tt], 0, 0, 0);
                accS[tt] = __builtin_amdgcn_mfma_f32_16x16x32_bf16(aQ[kf], bfr[1][tt][kf], accS[tt], 0, 0, 0);
            }

#pragma unroll
        for (int r = 0; r < 4; r++) {
            int node = tb16 + 4 * hi + r;
            if (node >= n) continue;
            int hd = hist[loc16 + 4 * hi + r];
            float di = hd > 0 ? rsqrtf((float)hd) : 0.0f;
            float y0 = accY[0][r], y1 = accY[1][r], y2 = accY[2][r], y3 = accY[3][r];
            float s0 = accS[0][r], s1 = accS[1][r], s2 = accS[2][r], s3 = accS[3][r];
            size_t b32 = (size_t)node * 32;
            y1p[b32 + L]      = pk2(y0 + bs0, y1 + bs1);   // dims (L, 16+L)
            y1p[b32 + 16 + L] = pk2(y2 + bs2, y3 + bs3);   // dims (32+L, 48+L)
            float z0 = di * (y0 + s0) * ZSCALE;
            float z1 = di * (y1 + s1) * ZSCALE;
            float z2 = di * (y2 + s2) * ZSCALE;
            float z3 = di * (y3 + s3) * ZSCALE;
            int w = __builtin_amdgcn_cvt_pk_fp8_f32(z0, z1, 0, false);
            w = __builtin_amdgcn_cvt_pk_fp8_f32(z2, z3, w, true);
            zp8[(size_t)node * 16 + L] = (unsigned int)w;
        }
    }
}

// ---------------- fp8 gather-sum ----------------
// 16-lane group per node, 4 nodes/wave. z-row = 64B (one line); lane l's
// dword holds fp8 dims {l, 16+l, 32+l, 48+l} (scaled). y1 bf16, out fp32.
__global__ __launch_bounds__(256, 8) void k_main(
    const unsigned int* __restrict__ zp8, const unsigned int* __restrict__ y1p,
    const int2* __restrict__ sse, const int* __restrict__ scol,
    const float* __restrict__ dinv, float* __restrict__ outf, int n) {
    int tid = threadIdx.x;
    int wave = tid >> 6, lane = tid & 63, g = lane >> 4, l = lane & 15;
    int i = blockIdx.x * 16 + wave * 4 + g;
    bool valid = i < n;
    int ii = valid ? i : 0;
    int2 se = sse[ii];
    int s0 = se.x;
    int s1 = valid ? se.y : se.x;

    float4 acc = make_float4(0.f, 0.f, 0.f, 0.f);
    for (int e = s0; e < s1; e += 16) {
        int cnt = s1 - e;
        cnt = cnt > 16 ? 16 : cnt;
        int jv = scol[e + (l < cnt ? l : 0)];
#pragma unroll 8
        for (int k = 0; k < 16; k++) {
            int j = __shfl(jv, (g << 4) + k, 64);
            float m = (k < cnt) ? 1.0f : 0.0f;
            unsigned int w = zp8[(size_t)j * 16 + l];
            acc.x = fmaf(__builtin_amdgcn_cvt_f32_fp8(w, 0), m, acc.x);  // dim l
            acc.y = fmaf(__builtin_amdgcn_cvt_f32_fp8(w, 1), m, acc.y);  // dim 16+l
            acc.z = fmaf(__builtin_amdgcn_cvt_f32_fp8(w, 2), m, acc.z);  // dim 32+l
            acc.w = fmaf(__builtin_amdgcn_cvt_f32_fp8(w, 3), m, acc.w);  // dim 48+l
        }
    }
    if (valid) {
        float ds = dinv[i] * ZINV;
        unsigned int ya = y1p[(size_t)i * 32 + l];        // dims (l, 16+l)
        unsigned int yb = y1p[(size_t)i * 32 + 16 + l];   // dims (32+l, 48+l)
        size_t base = (size_t)i * 64;
        outf[base + l]      = fmaf(ds, acc.x, bflo(ya));
        outf[base + 16 + l] = fmaf(ds, acc.y, bfhi(ya));
        outf[base + 32 + l] = fmaf(ds, acc.z, bflo(yb));
        outf[base + 48 + l] = fmaf(ds, acc.w, bfhi(yb));
    }
}

extern "C" void kernel_launch(void* const* d_in, const int* in_sizes, int n_in,
                              void* d_out, int out_size, void* d_ws, size_t ws_size,
                              hipStream_t stream) {
    const float* embed = (const float*)d_in[0];
    const int* row = (const int*)d_in[1];
    const int* col = (const int*)d_in[2];
    const float* W1 = (const float*)d_in[3];
    const float* b1 = (const float*)d_in[4];
    const float* W2 = (const float*)d_in[5];
    const float* b2 = (const float*)d_in[6];
    float* out = (float*)d_out;

    int n = in_sizes[0] / 64;   // 144242
    int E = in_sizes[1];        // 2,000,000
    int Eh = E / 2;             // symmetric pairs: row=[u;it], col=[it;u]
    int nbuck = (n + 255) >> 8; // 564
    size_t n64 = (size_t)n * 64;
    if (nbuck > MAXBUCK) return;  // fixed-size LDS guard
    if (n >= (1 << 18)) return;   // rec packing guard (v<<8 must fit 32b)

    char* ws = (char*)d_ws;
    size_t off = 0;
    unsigned int* zp8 = (unsigned int*)(ws + off); off += n64;            // 9.2 MB (fp8)
    unsigned int* y1p = (unsigned int*)(ws + off); off += n64 * 2;        // 18.5 MB
    unsigned int* rec = (unsigned int*)(ws + off); off += (size_t)E * 4;  // 8 MB
    int* scol = (int*)(ws + off);                  off += (size_t)E * 4;  // 8 MB
    int* H = (int*)(ws + off);                     off += (size_t)NB * nbuck * 4;
    int* Off = (int*)(ws + off);                   off += (size_t)nbuck * NB * 4;
    int* btot = (int*)(ws + off);                  off += (size_t)nbuck * 4;
    int* bbase = (int*)(ws + off);                 off += (size_t)nbuck * 4;
    int2* sse = (int2*)(ws + off);                 off += (size_t)n * 8;
    float* dinv = (float*)(ws + off);              off += (size_t)n * 4;
    int4* wfrag = (int4*)(ws + off);               off += 1024 * 16;      // 16 KB
    int* galloc = (int*)(ws + off);                off += 64;

    if (off > ws_size) return;  // ws too small -> out stays zero (0.707 absmax signal)

    k1_count<<<NB, 256, 0, stream>>>(row, col, H, galloc, Eh, nbuck);
    k2_colscan<<<nbuck, 256, 0, stream>>>(H, Off, btot, bbase, galloc,
                                          (const float4*)W1, (const float4*)W2,
                                          wfrag, nbuck);
    k3_scatter<<<NB, 256, 0, stream>>>(row, col, Off, bbase, rec, Eh, nbuck);
    k4_fused<<<nbuck, 256, 0, stream>>>(rec, bbase, btot, sse, dinv, scol,
                                        (const float4*)embed, wfrag, b1, b2,
                                        y1p, zp8, n);
    k_main<<<(n + 15) / 16, 256, 0, stream>>>(zp8, y1p, sse, scol, dinv, out, n);
}